// Round 5
// baseline (444.518 us; speedup 1.0000x reference)
//
#include <hip/hip_runtime.h>
#include <hip/hip_bf16.h>
#include <stdint.h>

typedef __bf16 bf16;
typedef __attribute__((ext_vector_type(8))) __bf16 bf16x8;
typedef __attribute__((ext_vector_type(4))) __bf16 bf16x4;
typedef __attribute__((ext_vector_type(4))) float f32x4;
typedef __attribute__((ext_vector_type(16))) float f32x16;
typedef __attribute__((ext_vector_type(4))) uint32_t u32x4;

#define S_LEN 2048
#define DMODEL 1024
#define NH 16
#define BATCH 4

// ws layout (bf16 elements): Xc 3*NX | Wc 3*NW | Pp 3*NX  (~102 MB)
#define NX 8388608u
#define NW 1048576u
#define WC_OFF (3u * NX)
#define PP_OFF (WC_OFF + 3u * NW)

static __device__ __forceinline__ void gload_lds16(const void* g, void* l) {
  __builtin_amdgcn_global_load_lds(
      (const __attribute__((address_space(1))) void*)(g),
      (__attribute__((address_space(3))) void*)(l), 16, 0, 0);
}

static __device__ __forceinline__ void wait_lds() {
  asm volatile("s_waitcnt lgkmcnt(0)" ::: "memory");
}

// pack 2 f32 -> 1 dword of 2 bf16 (no builtin on gfx950, m240)
static __device__ __forceinline__ uint32_t cvtpk(float lo, float hi) {
  uint32_t r;
  asm("v_cvt_pk_bf16_f32 %0, %1, %2" : "=v"(r) : "v"(lo), "v"(hi));
  return r;
}
// swap row1(a) <-> row0(b)  (rows = lane halves)
static __device__ __forceinline__ void pl32swap(uint32_t& a, uint32_t& b) {
  asm volatile("v_permlane32_swap_b32 %0, %1" : "+v"(a), "+v"(b));
}

// ---------------------------------------------------------------- convert
struct CvtArgs {
  const float* s[6];
  bf16* d[6];
  int n[6];
};

__global__ __launch_bounds__(256) void cvt_f32_bf16(CvtArgs a) {
  const int ai = blockIdx.y;
  const float* __restrict__ s = a.s[ai];
  bf16* __restrict__ d = a.d[ai];
  const int n = a.n[ai];
  const int i = (blockIdx.x * 256 + threadIdx.x) * 8;
  if (i >= n) return;
  const float4* sp = reinterpret_cast<const float4*>(s + i);
  float4 x = sp[0];
  float4 y = sp[1];
  bf16x8 o;
  o[0] = (bf16)x.x; o[1] = (bf16)x.y; o[2] = (bf16)x.z; o[3] = (bf16)x.w;
  o[4] = (bf16)y.x; o[5] = (bf16)y.y; o[6] = (bf16)y.z; o[7] = (bf16)y.w;
  *reinterpret_cast<bf16x8*>(d + i) = o;
}

// ---------------------------------------------------------------- projection
// (unchanged — attn is this round's single experiment)
__global__ __launch_bounds__(256, 3) void proj_gemm(const bf16* __restrict__ Xc,
                                                    const bf16* __restrict__ Wc,
                                                    bf16* __restrict__ Yp) {
  const int z = blockIdx.z;
  const bf16* __restrict__ X = Xc + (size_t)z * NX;
  const bf16* __restrict__ W = Wc + (size_t)z * NW;
  bf16* __restrict__ Y = Yp + (size_t)z * NX;

  __shared__ bf16 ldsA[2][128 * 32];
  __shared__ bf16 ldsB[2][128 * 32];

  const int tid = threadIdx.x;
  const int lane = tid & 63;
  const int w = tid >> 6;
  const int wr = w >> 1, wc = w & 1;
  const int r16 = lane & 15, g4 = lane >> 4;
  const int m0 = blockIdx.x * 128, n0 = blockIdx.y * 128;

  f32x4 acc[4][4];
#pragma unroll
  for (int mi = 0; mi < 4; mi++)
#pragma unroll
    for (int ni = 0; ni < 4; ni++) acc[mi][ni] = (f32x4){0.f, 0.f, 0.f, 0.f};

  const int rowa = tid >> 2;
  const int cola = (tid & 3) * 8;

  auto stage = [&](int buf, int k0) {
    gload_lds16(X + (size_t)(m0 + rowa) * DMODEL + k0 + cola, &ldsA[buf][tid * 8]);
    gload_lds16(X + (size_t)(m0 + 64 + rowa) * DMODEL + k0 + cola,
                &ldsA[buf][2048 + tid * 8]);
    gload_lds16(W + (size_t)(n0 + rowa) * DMODEL + k0 + cola, &ldsB[buf][tid * 8]);
    gload_lds16(W + (size_t)(n0 + 64 + rowa) * DMODEL + k0 + cola,
                &ldsB[buf][2048 + tid * 8]);
  };

  stage(0, 0);
  __syncthreads();
  int cur = 0;

  for (int k0 = 0; k0 < DMODEL; k0 += 32) {
    if (k0 + 32 < DMODEL) stage(cur ^ 1, k0 + 32);

    bf16x8 af[4], bfr[4];
#pragma unroll
    for (int mi = 0; mi < 4; mi++)
      af[mi] = *reinterpret_cast<const bf16x8*>(
          &ldsA[cur][(wr * 64 + mi * 16 + r16) * 32 + g4 * 8]);
#pragma unroll
    for (int ni = 0; ni < 4; ni++)
      bfr[ni] = *reinterpret_cast<const bf16x8*>(
          &ldsB[cur][(wc * 64 + ni * 16 + r16) * 32 + g4 * 8]);
    __builtin_amdgcn_s_setprio(1);
#pragma unroll
    for (int mi = 0; mi < 4; mi++)
#pragma unroll
      for (int ni = 0; ni < 4; ni++)
        acc[mi][ni] = __builtin_amdgcn_mfma_f32_16x16x32_bf16(
            af[mi], bfr[ni], acc[mi][ni], 0, 0, 0);
    __builtin_amdgcn_s_setprio(0);
    __syncthreads();
    cur ^= 1;
  }

  float* shf = reinterpret_cast<float*>(&ldsA[0][0]) + w * 1024;
#pragma unroll
  for (int mi = 0; mi < 4; mi++) {
#pragma unroll
    for (int ni = 0; ni < 4; ni++)
#pragma unroll
      for (int i = 0; i < 4; i++) {
        const int rl = g4 * 4 + i;
        const int cl = ni * 16 + r16;
        shf[rl * 64 + ((cl + 4 * rl) & 63)] = acc[mi][ni][i];
      }
    wait_lds();
#pragma unroll
    for (int cc = 0; cc < 4; cc++) {
      const int row = g4 + cc * 4;
      const int c0 = r16 * 4;
      const f32x4 vv = *reinterpret_cast<const f32x4*>(
          &shf[row * 64 + ((c0 + 4 * row) & 63)]);
      bf16x4 o;
      o[0] = (bf16)vv[0]; o[1] = (bf16)vv[1]; o[2] = (bf16)vv[2]; o[3] = (bf16)vv[3];
      *reinterpret_cast<bf16x4*>(
          Y + (size_t)(m0 + wr * 64 + mi * 16 + row) * DMODEL + n0 + wc * 64 + c0) = o;
    }
    wait_lds();
  }
}

// ---------------------------------------------------------------- attention
// 32x32 MFMA flash attn, FIXED-SHIFT softmax (exact: softmax is shift-
// invariant; input stats give |score*log2e/32| < 0.05 << M2=1, and fp32 range
// makes overflow impossible for any plausible scores). No running max, no
// rescale, no cross-lane ops in the K-loop. Row-sum l accumulated by a
// ones-column MFMA into lacc (same C/D row layout as oacc -> epilogue needs
// no shuffles either). P kept in registers via cvt_pk + permlane32_swap.
__global__ __launch_bounds__(256, 4) void attn_kernel(const bf16* __restrict__ Qp,
                                                      const bf16* __restrict__ Kp,
                                                      const bf16* __restrict__ Vp,
                                                      float* __restrict__ Out) {
  // ldsK  slot [kv][c'] holds K[kv][c' ^ 8*(kv&7)]
  // ldsVt slot [d][c']  holds V[c' ^ 8*(((d>>3)^d)&7)][d]
  __shared__ bf16 ldsK[2][64 * 64];
  __shared__ bf16 ldsVt[2][64 * 64];

  const int tid = threadIdx.x;
  const int lane = tid & 63;
  const int w = tid >> 6;
  const int l31 = lane & 31, hi = lane >> 5;
  const int b = blockIdx.z, h = blockIdx.y;
  const int q0 = blockIdx.x * 128 + w * 32;

  // Q fragments (B-operand, 32x32x16): lane holds Q[q0+l31][s*16+hi*8+j]
  bf16x8 qf[4];
#pragma unroll
  for (int s = 0; s < 4; s++)
    qf[s] = *reinterpret_cast<const bf16x8*>(
        Qp + (size_t)(b * S_LEN + q0 + l31) * DMODEL + h * 64 + s * 16 + hi * 8);

  f32x16 oacc[2], lacc;
  oacc[0] = (f32x16)0.f;
  oacc[1] = (f32x16)0.f;
  lacc = (f32x16)0.f;

  bf16x8 ones;
#pragma unroll
  for (int j = 0; j < 8; j++) ones[j] = (bf16)1.0f;

  const float C2 = 0.04508422002778011f;  // log2(e)/32
  const float M2 = 1.0f;                  // fixed shift (exp2 domain)

  const int srow = tid >> 3;              // 0..31
  const int scol = (tid & 7) * 8;         // 0..56
  const int kswz = (srow & 7) * 8;        // K source pre-swizzle (G21)

  auto stageK = [&](int buf, int kv0) {
    gload_lds16(Kp + (size_t)(b * S_LEN + kv0 + srow) * DMODEL + h * 64 + (scol ^ kswz),
                &ldsK[buf][tid * 8]);
    gload_lds16(Kp + (size_t)(b * S_LEN + kv0 + 32 + srow) * DMODEL + h * 64 + (scol ^ kswz),
                &ldsK[buf][2048 + tid * 8]);
  };
  bf16x8 vpre0, vpre1;
  auto loadV = [&](int kv0) {
    vpre0 = *reinterpret_cast<const bf16x8*>(
        Vp + (size_t)(b * S_LEN + kv0 + srow) * DMODEL + h * 64 + scol);
    vpre1 = *reinterpret_cast<const bf16x8*>(
        Vp + (size_t)(b * S_LEN + kv0 + 32 + srow) * DMODEL + h * 64 + scol);
  };
  auto writeV = [&](int buf) {
#pragma unroll
    for (int j = 0; j < 8; j++) {
      const int d = scol + j;
      const int vsw = (((scol >> 3) ^ j) & 7) * 8;
      ldsVt[buf][d * 64 + (srow ^ vsw)] = vpre0[j];
      ldsVt[buf][d * 64 + ((srow + 32) ^ vsw)] = vpre1[j];
    }
  };

  stageK(0, 0);
  loadV(0);
  writeV(0);
  __syncthreads();
  int cur = 0;

  union U { u32x4 u; bf16x8 v; };

  constexpr int NT = S_LEN / 64;
  for (int it = 0; it < NT; it++) {
    const bool pf = (it + 1 < NT);
    if (pf) {
      stageK(cur ^ 1, (it + 1) * 64);
      loadV((it + 1) * 64);
    }

    // --- per kvh half: QK^T then immediate exp+pack (keeps live sacc at 16)
    U pa[2][2];  // pa[kvh][sh]: A[q=l31][kv = kvh*32 + sh*16 + hi*8 + j]
#pragma unroll
    for (int kvh = 0; kvh < 2; kvh++) {
      f32x16 sacc = (f32x16)0.f;
      const int kv = kvh * 32 + l31;
      __builtin_amdgcn_s_setprio(1);
#pragma unroll
      for (int s = 0; s < 4; s++) {
        const bf16x8 kf = *reinterpret_cast<const bf16x8*>(
            &ldsK[cur][kv * 64 + ((s * 16 + hi * 8) ^ ((l31 & 7) * 8))]);
        sacc = __builtin_amdgcn_mfma_f32_32x32x16_bf16(kf, qf[s], sacc, 0, 0, 0);
      }
      __builtin_amdgcn_s_setprio(0);

      // p = 2^(s*C2 - M2); element-independent, no reductions
#pragma unroll
      for (int r = 0; r < 16; r++) sacc[r] = exp2f(fmaf(sacc[r], C2, -M2));

      uint32_t a0 = cvtpk(sacc[0], sacc[1]);
      uint32_t b0 = cvtpk(sacc[4], sacc[5]);
      pl32swap(a0, b0);
      uint32_t a1 = cvtpk(sacc[2], sacc[3]);
      uint32_t b1 = cvtpk(sacc[6], sacc[7]);
      pl32swap(a1, b1);
      pa[kvh][0].u = (u32x4){a0, a1, b0, b1};
      uint32_t a2 = cvtpk(sacc[8], sacc[9]);
      uint32_t b2 = cvtpk(sacc[12], sacc[13]);
      pl32swap(a2, b2);
      uint32_t a3 = cvtpk(sacc[10], sacc[11]);
      uint32_t b3 = cvtpk(sacc[14], sacc[15]);
      pl32swap(a3, b3);
      pa[kvh][1].u = (u32x4){a2, a3, b2, b3};
    }

    // --- PV + row-sum:  oacc[db] += P*V ;  lacc += P*ones
    __builtin_amdgcn_s_setprio(1);
#pragma unroll
    for (int kvh = 0; kvh < 2; kvh++)
#pragma unroll
      for (int sh = 0; sh < 2; sh++) {
        const int kvb = kvh * 32 + sh * 16 + hi * 8;
        lacc = __builtin_amdgcn_mfma_f32_32x32x16_bf16(pa[kvh][sh].v, ones,
                                                       lacc, 0, 0, 0);
#pragma unroll
        for (int db = 0; db < 2; db++) {
          const int d = db * 32 + l31;
          const bf16x8 vf = *reinterpret_cast<const bf16x8*>(
              &ldsVt[cur][d * 64 + (kvb ^ ((((d >> 3) ^ d) & 7) * 8))]);
          oacc[db] = __builtin_amdgcn_mfma_f32_32x32x16_bf16(pa[kvh][sh].v, vf,
                                                             oacc[db], 0, 0, 0);
        }
      }
    __builtin_amdgcn_s_setprio(0);

    if (pf) writeV(cur ^ 1);
    __syncthreads();
    cur ^= 1;
  }

  // --- epilogue: Out[b][q0+qrow][h*64 + db*32 + l31] = oacc/lacc
  // lacc already has row layout (all cols equal) -> no shuffles.
#pragma unroll
  for (int r = 0; r < 16; r++) {
    const int qrow = (r & 3) + 8 * (r >> 2) + 4 * hi;
    const float inv_l = 1.0f / lacc[r];
    float* op = Out + (size_t)(b * S_LEN + q0 + qrow) * DMODEL + h * 64 + l31;
    op[0] = oacc[0][r] * inv_l;
    op[32] = oacc[1][r] * inv_l;
  }
}

// ---------------------------------------------------------------- launch
extern "C" void kernel_launch(void* const* d_in, const int* in_sizes, int n_in,
                              void* d_out, int out_size, void* d_ws, size_t ws_size,
                              hipStream_t stream) {
  const float* q = (const float*)d_in[0];
  const float* k = (const float*)d_in[1];
  const float* v = (const float*)d_in[2];
  const float* wq = (const float*)d_in[3];
  const float* wk = (const float*)d_in[4];
  const float* wv = (const float*)d_in[5];
  bf16* ws = (bf16*)d_ws;
  bf16* Xc = ws;
  bf16* Wc = ws + WC_OFF;
  bf16* Pp = ws + PP_OFF;
  float* out = (float*)d_out;

  CvtArgs ca;
  ca.s[0] = q;  ca.s[1] = k;  ca.s[2] = v;
  ca.s[3] = wq; ca.s[4] = wk; ca.s[5] = wv;
  ca.d[0] = Xc;          ca.d[1] = Xc + NX;     ca.d[2] = Xc + 2 * NX;
  ca.d[3] = Wc;          ca.d[4] = Wc + NW;     ca.d[5] = Wc + 2 * NW;
  ca.n[0] = ca.n[1] = ca.n[2] = (int)NX;
  ca.n[3] = ca.n[4] = ca.n[5] = (int)NW;
  cvt_f32_bf16<<<dim3(4096, 6, 1), dim3(256), 0, stream>>>(ca);

  proj_gemm<<<dim3(64, 8, 3), dim3(256), 0, stream>>>(Xc, Wc, Pp);

  attn_kernel<<<dim3(S_LEN / 128, NH, BATCH), dim3(256), 0, stream>>>(
      Pp, Pp + NX, Pp + 2 * NX, out);
}

// Round 6
// 440.440 us; speedup vs baseline: 1.0093x; 1.0093x over previous
//
#include <hip/hip_runtime.h>
#include <hip/hip_bf16.h>
#include <stdint.h>

typedef __bf16 bf16;
typedef __attribute__((ext_vector_type(8))) __bf16 bf16x8;
typedef __attribute__((ext_vector_type(4))) __bf16 bf16x4;
typedef __attribute__((ext_vector_type(4))) float f32x4;
typedef __attribute__((ext_vector_type(16))) float f32x16;
typedef __attribute__((ext_vector_type(4))) uint32_t u32x4;

#define S_LEN 2048
#define DMODEL 1024
#define NH 16
#define BATCH 4

// ws layout (bf16 elements): Xc 3*NX | Wc 3*NW | Pp 3*NX  (~102 MB)
// Pp region 2 holds V^T as [b*NH+h][64][2048] (same NX footprint).
#define NX 8388608u
#define NW 1048576u
#define WC_OFF (3u * NX)
#define PP_OFF (WC_OFF + 3u * NW)

static __device__ __forceinline__ void gload_lds16(const void* g, void* l) {
  __builtin_amdgcn_global_load_lds(
      (const __attribute__((address_space(1))) void*)(g),
      (__attribute__((address_space(3))) void*)(l), 16, 0, 0);
}

static __device__ __forceinline__ void wait_lds() {
  asm volatile("s_waitcnt lgkmcnt(0)" ::: "memory");
}

// pack 2 f32 -> 1 dword of 2 bf16 (no builtin on gfx950, m240)
static __device__ __forceinline__ uint32_t cvtpk(float lo, float hi) {
  uint32_t r;
  asm("v_cvt_pk_bf16_f32 %0, %1, %2" : "=v"(r) : "v"(lo), "v"(hi));
  return r;
}
// swap row1(a) <-> row0(b)  (rows = lane halves)
static __device__ __forceinline__ void pl32swap(uint32_t& a, uint32_t& b) {
  asm volatile("v_permlane32_swap_b32 %0, %1" : "+v"(a), "+v"(b));
}

// ---------------------------------------------------------------- convert
struct CvtArgs {
  const float* s[6];
  bf16* d[6];
  int n[6];
};

__global__ __launch_bounds__(256) void cvt_f32_bf16(CvtArgs a) {
  const int ai = blockIdx.y;
  const float* __restrict__ s = a.s[ai];
  bf16* __restrict__ d = a.d[ai];
  const int n = a.n[ai];
  const int i = (blockIdx.x * 256 + threadIdx.x) * 8;
  if (i >= n) return;
  const float4* sp = reinterpret_cast<const float4*>(s + i);
  float4 x = sp[0];
  float4 y = sp[1];
  bf16x8 o;
  o[0] = (bf16)x.x; o[1] = (bf16)x.y; o[2] = (bf16)x.z; o[3] = (bf16)x.w;
  o[4] = (bf16)y.x; o[5] = (bf16)y.y; o[6] = (bf16)y.z; o[7] = (bf16)y.w;
  *reinterpret_cast<bf16x8*>(d + i) = o;
}

// ---------------------------------------------------------------- projection
// Y[m][n] = sum_k X[m][k]*W[n][k].  128x128 tile, BK=32, 4 waves (2x2 quads).
// z==0,1 (Q,K): normal [8192][1024] output.
// z==2 (V): TRANSPOSED output Vt[(b*NH+h)*64+d][kv] = [4096][2048] so the
//           attention kernel can read V fragments as contiguous 16B loads.
__global__ __launch_bounds__(256, 3) void proj_gemm(const bf16* __restrict__ Xc,
                                                    const bf16* __restrict__ Wc,
                                                    bf16* __restrict__ Yp) {
  const int z = blockIdx.z;
  const bf16* __restrict__ X = Xc + (size_t)z * NX;
  const bf16* __restrict__ W = Wc + (size_t)z * NW;
  bf16* __restrict__ Y = Yp + (size_t)z * NX;

  __shared__ bf16 ldsA[2][128 * 32];
  __shared__ bf16 ldsB[2][128 * 32];

  const int tid = threadIdx.x;
  const int lane = tid & 63;
  const int w = tid >> 6;
  const int wr = w >> 1, wc = w & 1;
  const int r16 = lane & 15, g4 = lane >> 4;
  const int m0 = blockIdx.x * 128, n0 = blockIdx.y * 128;

  f32x4 acc[4][4];
#pragma unroll
  for (int mi = 0; mi < 4; mi++)
#pragma unroll
    for (int ni = 0; ni < 4; ni++) acc[mi][ni] = (f32x4){0.f, 0.f, 0.f, 0.f};

  const int rowa = tid >> 2;
  const int cola = (tid & 3) * 8;

  auto stage = [&](int buf, int k0) {
    gload_lds16(X + (size_t)(m0 + rowa) * DMODEL + k0 + cola, &ldsA[buf][tid * 8]);
    gload_lds16(X + (size_t)(m0 + 64 + rowa) * DMODEL + k0 + cola,
                &ldsA[buf][2048 + tid * 8]);
    gload_lds16(W + (size_t)(n0 + rowa) * DMODEL + k0 + cola, &ldsB[buf][tid * 8]);
    gload_lds16(W + (size_t)(n0 + 64 + rowa) * DMODEL + k0 + cola,
                &ldsB[buf][2048 + tid * 8]);
  };

  stage(0, 0);
  __syncthreads();
  int cur = 0;

  for (int k0 = 0; k0 < DMODEL; k0 += 32) {
    if (k0 + 32 < DMODEL) stage(cur ^ 1, k0 + 32);

    bf16x8 af[4], bfr[4];
#pragma unroll
    for (int mi = 0; mi < 4; mi++)
      af[mi] = *reinterpret_cast<const bf16x8*>(
          &ldsA[cur][(wr * 64 + mi * 16 + r16) * 32 + g4 * 8]);
#pragma unroll
    for (int ni = 0; ni < 4; ni++)
      bfr[ni] = *reinterpret_cast<const bf16x8*>(
          &ldsB[cur][(wc * 64 + ni * 16 + r16) * 32 + g4 * 8]);
    __builtin_amdgcn_s_setprio(1);
#pragma unroll
    for (int mi = 0; mi < 4; mi++)
#pragma unroll
      for (int ni = 0; ni < 4; ni++)
        acc[mi][ni] = __builtin_amdgcn_mfma_f32_16x16x32_bf16(
            af[mi], bfr[ni], acc[mi][ni], 0, 0, 0);
    __builtin_amdgcn_s_setprio(0);
    __syncthreads();
    cur ^= 1;
  }

  // ---- epilogue via per-wave-private LDS transpose buffer (4KB each)
  float* shf = reinterpret_cast<float*>(&ldsA[0][0]) + w * 1024;  // 16x64 f32
  const int bq = m0 >> 11;              // batch index (2048 rows per batch)
  const int rloc = (m0 & 2047) + wr * 64;  // local kv base for V^T
#pragma unroll
  for (int mi = 0; mi < 4; mi++) {
#pragma unroll
    for (int ni = 0; ni < 4; ni++)
#pragma unroll
      for (int i = 0; i < 4; i++) {
        const int rl = g4 * 4 + i;             // C/D row (m89-verified)
        const int cl = ni * 16 + r16;          // C/D col
        shf[rl * 64 + ((cl + 4 * rl) & 63)] = acc[mi][ni][i];  // rot-swizzle
      }
    wait_lds();  // own-wave ds_write -> ds_read ordering
    if (z == 2) {
      // transposed read: fixed col cl, 4 consecutive rows -> Vt[d][kv0..3]
      // banks: (cl + 4*rl) mod 32 -> 2 lanes/bank (free, checked)
#pragma unroll
      for (int cc = 0; cc < 4; cc++) {
        const int cl = (lane >> 2) + cc * 16;
        const int rl0 = (lane & 3) * 4;
        float v0 = shf[(rl0 + 0) * 64 + ((cl + 4 * (rl0 + 0)) & 63)];
        float v1 = shf[(rl0 + 1) * 64 + ((cl + 4 * (rl0 + 1)) & 63)];
        float v2 = shf[(rl0 + 2) * 64 + ((cl + 4 * (rl0 + 2)) & 63)];
        float v3 = shf[(rl0 + 3) * 64 + ((cl + 4 * (rl0 + 3)) & 63)];
        bf16x4 o;
        o[0] = (bf16)v0; o[1] = (bf16)v1; o[2] = (bf16)v2; o[3] = (bf16)v3;
        // d_glob = bq*1024 + n0 + wc*64 + cl  (row of [4096][2048])
        *reinterpret_cast<bf16x4*>(
            Y + (size_t)(bq * 1024 + n0 + wc * 64 + cl) * 2048 +
            rloc + mi * 16 + rl0) = o;
      }
    } else {
#pragma unroll
      for (int cc = 0; cc < 4; cc++) {
        const int row = g4 + cc * 4;
        const int c0 = r16 * 4;
        const f32x4 vv = *reinterpret_cast<const f32x4*>(
            &shf[row * 64 + ((c0 + 4 * row) & 63)]);
        bf16x4 o;
        o[0] = (bf16)vv[0]; o[1] = (bf16)vv[1]; o[2] = (bf16)vv[2]; o[3] = (bf16)vv[3];
        *reinterpret_cast<bf16x4*>(
            Y + (size_t)(m0 + wr * 64 + mi * 16 + row) * DMODEL + n0 + wc * 64 + c0) = o;
      }
    }
    wait_lds();  // reads done before next mi overwrites the same 4KB
  }
}

// ---------------------------------------------------------------- attention
// 32x32 MFMA flash attn, ZERO LDS / ZERO barriers. K and V^T fragments are
// read directly from global (per-(b,h) working set 512KB = L2-resident; per-
// tile 16KB = L1-resident), so waves are fully independent and the compiler
// pipelines loads across tiles. Fixed-shift exp2 softmax (exact by shift
// invariance; |score*C2| << M2=1, fp32 overflow impossible). Row-sum via
// ones-MFMA rides the idle matrix pipe; epilogue shuffle-free.
__global__ __launch_bounds__(256, 4) void attn_kernel(const bf16* __restrict__ Qp,
                                                      const bf16* __restrict__ Kp,
                                                      const bf16* __restrict__ Vtp,
                                                      float* __restrict__ Out) {
  const int tid = threadIdx.x;
  const int lane = tid & 63;
  const int w = tid >> 6;
  const int l31 = lane & 31, hi = lane >> 5;
  const int bh = blockIdx.x;  // b*NH + h  (fast dim -> q-tiles of same bh
  const int b = bh >> 4;      //  land on one XCD: linear-id stride 64 = 0 mod 8)
  const int h = bh & 15;
  const int q0 = blockIdx.y * 128 + w * 32;

  const bf16* __restrict__ Qb = Qp + (size_t)(b * S_LEN) * DMODEL + h * 64;
  const bf16* __restrict__ Kb = Kp + (size_t)(b * S_LEN) * DMODEL + h * 64;
  const bf16* __restrict__ Vtb = Vtp + (size_t)bh * 64 * S_LEN;  // [64][2048]

  // Q fragments (B-operand, 32x32x16): lane holds Q[q0+l31][s*16+hi*8+j]
  bf16x8 qf[4];
#pragma unroll
  for (int s = 0; s < 4; s++)
    qf[s] = *reinterpret_cast<const bf16x8*>(
        &Qb[(size_t)(q0 + l31) * DMODEL + s * 16 + hi * 8]);

  f32x16 oacc[2], lacc;
  oacc[0] = (f32x16)0.f;
  oacc[1] = (f32x16)0.f;
  lacc = (f32x16)0.f;

  bf16x8 ones;
#pragma unroll
  for (int j = 0; j < 8; j++) ones[j] = (bf16)1.0f;

  const float C2 = 0.04508422002778011f;  // log2(e)/32
  const float M2 = 1.0f;                  // fixed shift (exp2 domain)

  union U { u32x4 u; bf16x8 v; };

  constexpr int NT = S_LEN / 64;
  for (int it = 0; it < NT; it++) {
    const int kv0 = it * 64;

    // --- QK^T per kv-half, immediate exp+pack (live sacc = 16 regs)
    U pa[2][2];  // pa[kvh][sh]: A[q=l31][kv = kvh*32 + sh*16 + hi*8 + j]
#pragma unroll
    for (int kvh = 0; kvh < 2; kvh++) {
      f32x16 sacc = (f32x16)0.f;
      const bf16* krow = &Kb[(size_t)(kv0 + kvh * 32 + l31) * DMODEL];
      __builtin_amdgcn_s_setprio(1);
#pragma unroll
      for (int s = 0; s < 4; s++) {
        const bf16x8 kf = *reinterpret_cast<const bf16x8*>(&krow[s * 16 + hi * 8]);
        sacc = __builtin_amdgcn_mfma_f32_32x32x16_bf16(kf, qf[s], sacc, 0, 0, 0);
      }
      __builtin_amdgcn_s_setprio(0);

      // p = 2^(s*C2 - M2); element-independent, no reductions
#pragma unroll
      for (int r = 0; r < 16; r++) sacc[r] = exp2f(fmaf(sacc[r], C2, -M2));

      uint32_t a0 = cvtpk(sacc[0], sacc[1]);
      uint32_t b0 = cvtpk(sacc[4], sacc[5]);
      pl32swap(a0, b0);
      uint32_t a1 = cvtpk(sacc[2], sacc[3]);
      uint32_t b1 = cvtpk(sacc[6], sacc[7]);
      pl32swap(a1, b1);
      pa[kvh][0].u = (u32x4){a0, a1, b0, b1};
      uint32_t a2 = cvtpk(sacc[8], sacc[9]);
      uint32_t b2 = cvtpk(sacc[12], sacc[13]);
      pl32swap(a2, b2);
      uint32_t a3 = cvtpk(sacc[10], sacc[11]);
      uint32_t b3 = cvtpk(sacc[14], sacc[15]);
      pl32swap(a3, b3);
      pa[kvh][1].u = (u32x4){a2, a3, b2, b3};
    }

    // --- PV + row-sum: oacc[db] += P*V^T-frag ; lacc += P*ones
    __builtin_amdgcn_s_setprio(1);
#pragma unroll
    for (int kvh = 0; kvh < 2; kvh++)
#pragma unroll
      for (int sh = 0; sh < 2; sh++) {
        const int kvb = kvh * 32 + sh * 16 + hi * 8;
        lacc = __builtin_amdgcn_mfma_f32_32x32x16_bf16(pa[kvh][sh].v, ones,
                                                       lacc, 0, 0, 0);
#pragma unroll
        for (int db = 0; db < 2; db++) {
          const bf16x8 vf = *reinterpret_cast<const bf16x8*>(
              &Vtb[(size_t)(db * 32 + l31) * S_LEN + kv0 + kvb]);
          oacc[db] = __builtin_amdgcn_mfma_f32_32x32x16_bf16(pa[kvh][sh].v, vf,
                                                             oacc[db], 0, 0, 0);
        }
      }
    __builtin_amdgcn_s_setprio(0);
  }

  // --- epilogue: Out[b][q0+qrow][h*64 + db*32 + l31] = oacc/lacc
#pragma unroll
  for (int r = 0; r < 16; r++) {
    const int qrow = (r & 3) + 8 * (r >> 2) + 4 * hi;
    const float inv_l = 1.0f / lacc[r];
    float* op = Out + (size_t)(b * S_LEN + q0 + qrow) * DMODEL + h * 64 + l31;
    op[0] = oacc[0][r] * inv_l;
    op[32] = oacc[1][r] * inv_l;
  }
}

// ---------------------------------------------------------------- launch
extern "C" void kernel_launch(void* const* d_in, const int* in_sizes, int n_in,
                              void* d_out, int out_size, void* d_ws, size_t ws_size,
                              hipStream_t stream) {
  const float* q = (const float*)d_in[0];
  const float* k = (const float*)d_in[1];
  const float* v = (const float*)d_in[2];
  const float* wq = (const float*)d_in[3];
  const float* wk = (const float*)d_in[4];
  const float* wv = (const float*)d_in[5];
  bf16* ws = (bf16*)d_ws;
  bf16* Xc = ws;
  bf16* Wc = ws + WC_OFF;
  bf16* Pp = ws + PP_OFF;
  float* out = (float*)d_out;

  CvtArgs ca;
  ca.s[0] = q;  ca.s[1] = k;  ca.s[2] = v;
  ca.s[3] = wq; ca.s[4] = wk; ca.s[5] = wv;
  ca.d[0] = Xc;          ca.d[1] = Xc + NX;     ca.d[2] = Xc + 2 * NX;
  ca.d[3] = Wc;          ca.d[4] = Wc + NW;     ca.d[5] = Wc + 2 * NW;
  ca.n[0] = ca.n[1] = ca.n[2] = (int)NX;
  ca.n[3] = ca.n[4] = ca.n[5] = (int)NW;
  cvt_f32_bf16<<<dim3(4096, 6, 1), dim3(256), 0, stream>>>(ca);

  proj_gemm<<<dim3(64, 8, 3), dim3(256), 0, stream>>>(Xc, Wc, Pp);

  // grid: x = b*NH+h (64), y = q-tile (16)  -> same-bh blocks share an XCD L2
  attn_kernel<<<dim3(BATCH * NH, S_LEN / 128, 1), dim3(256), 0, stream>>>(
      Pp, Pp + NX, Pp + 2 * NX, out);
}

// Round 8
// 317.424 us; speedup vs baseline: 1.4004x; 1.3875x over previous
//
#include <hip/hip_runtime.h>
#include <hip/hip_bf16.h>
#include <stdint.h>

typedef __bf16 bf16;
typedef __attribute__((ext_vector_type(8))) __bf16 bf16x8;
typedef __attribute__((ext_vector_type(4))) __bf16 bf16x4;
typedef __attribute__((ext_vector_type(4))) float f32x4;
typedef __attribute__((ext_vector_type(16))) float f32x16;
typedef __attribute__((ext_vector_type(4))) uint32_t u32x4;

#define S_LEN 2048
#define DMODEL 1024
#define NH 16
#define BATCH 4

// ws layout (bf16 elements): Xc 3*NX | Wc 3*NW | Pp 3*NX  (~102 MB)
// Pp region 2 holds V^T as [b*NH+h][64][2048] (same NX footprint).
#define NX 8388608u
#define NW 1048576u
#define WC_OFF (3u * NX)
#define PP_OFF (WC_OFF + 3u * NW)

static __device__ __forceinline__ void gload_lds16(const void* g, void* l) {
  __builtin_amdgcn_global_load_lds(
      (const __attribute__((address_space(1))) void*)(g),
      (__attribute__((address_space(3))) void*)(l), 16, 0, 0);
}

static __device__ __forceinline__ void wait_lds() {
  asm volatile("s_waitcnt lgkmcnt(0)" ::: "memory");
}
static __device__ __forceinline__ void barrier_raw() {
  asm volatile("s_barrier" ::: "memory");
}
static __device__ __forceinline__ void wait_vm4() {
  asm volatile("s_waitcnt vmcnt(4)" ::: "memory");
}
static __device__ __forceinline__ void wait_vm0() {
  asm volatile("s_waitcnt vmcnt(0)" ::: "memory");
}

// pack 2 f32 -> 1 dword of 2 bf16 (no builtin on gfx950, m240)
static __device__ __forceinline__ uint32_t cvtpk(float lo, float hi) {
  uint32_t r;
  asm("v_cvt_pk_bf16_f32 %0, %1, %2" : "=v"(r) : "v"(lo), "v"(hi));
  return r;
}
// swap row1(a) <-> row0(b)  (rows = lane halves)
static __device__ __forceinline__ void pl32swap(uint32_t& a, uint32_t& b) {
  asm volatile("v_permlane32_swap_b32 %0, %1" : "+v"(a), "+v"(b));
}

// ---------------------------------------------------------------- convert
struct CvtArgs {
  const float* s[6];
  bf16* d[6];
  int n[6];
};

__global__ __launch_bounds__(256) void cvt_f32_bf16(CvtArgs a) {
  const int ai = blockIdx.y;
  const float* __restrict__ s = a.s[ai];
  bf16* __restrict__ d = a.d[ai];
  const int n = a.n[ai];
  const int i = (blockIdx.x * 256 + threadIdx.x) * 8;
  if (i >= n) return;
  const float4* sp = reinterpret_cast<const float4*>(s + i);
  float4 x = sp[0];
  float4 y = sp[1];
  bf16x8 o;
  o[0] = (bf16)x.x; o[1] = (bf16)x.y; o[2] = (bf16)x.z; o[3] = (bf16)x.w;
  o[4] = (bf16)y.x; o[5] = (bf16)y.y; o[6] = (bf16)y.z; o[7] = (bf16)y.w;
  *reinterpret_cast<bf16x8*>(d + i) = o;
}

// ---------------------------------------------------------------- projection
// Y[m][n] = sum_k X[m][k]*W[n][k].  128x128 tile, BK=32, 4 waves (2x2 quads).
// 2-barrier counted-vmcnt pipeline (T4): prefetch DMA never drained to 0
// inside the loop. z==0,1: normal output. z==2: transposed V^T output.
__global__ __launch_bounds__(256, 3) void proj_gemm(const bf16* __restrict__ Xc,
                                                    const bf16* __restrict__ Wc,
                                                    bf16* __restrict__ Yp) {
  const int z = blockIdx.z;
  const bf16* __restrict__ X = Xc + (size_t)z * NX;
  const bf16* __restrict__ W = Wc + (size_t)z * NW;
  bf16* __restrict__ Y = Yp + (size_t)z * NX;

  __shared__ bf16 ldsA[2][128 * 32];
  __shared__ bf16 ldsB[2][128 * 32];

  const int tid = threadIdx.x;
  const int lane = tid & 63;
  const int w = tid >> 6;
  const int wr = w >> 1, wc = w & 1;
  const int r16 = lane & 15, g4 = lane >> 4;
  const int m0 = blockIdx.x * 128, n0 = blockIdx.y * 128;

  f32x4 acc[4][4];
#pragma unroll
  for (int mi = 0; mi < 4; mi++)
#pragma unroll
    for (int ni = 0; ni < 4; ni++) acc[mi][ni] = (f32x4){0.f, 0.f, 0.f, 0.f};

  const int rowa = tid >> 2;
  const int cola = (tid & 3) * 8;

  auto stage = [&](int buf, int k0) {
    gload_lds16(X + (size_t)(m0 + rowa) * DMODEL + k0 + cola, &ldsA[buf][tid * 8]);
    gload_lds16(X + (size_t)(m0 + 64 + rowa) * DMODEL + k0 + cola,
                &ldsA[buf][2048 + tid * 8]);
    gload_lds16(W + (size_t)(n0 + rowa) * DMODEL + k0 + cola, &ldsB[buf][tid * 8]);
    gload_lds16(W + (size_t)(n0 + 64 + rowa) * DMODEL + k0 + cola,
                &ldsB[buf][2048 + tid * 8]);
  };

  stage(0, 0);
  wait_vm0();
  barrier_raw();
  int cur = 0;

  for (int k0 = 0; k0 < DMODEL; k0 += 32) {
    const bool pf = (k0 + 32 < DMODEL);
    if (pf) {
      stage(cur ^ 1, k0 + 32);  // 4 DMA issued; fly across this K-step
      wait_vm4();               // cur's 4 (issued last iter) complete
    } else {
      wait_vm0();
    }
    barrier_raw();  // (A) all waves see cur staged

    bf16x8 af[4], bfr[4];
#pragma unroll
    for (int mi = 0; mi < 4; mi++)
      af[mi] = *reinterpret_cast<const bf16x8*>(
          &ldsA[cur][(wr * 64 + mi * 16 + r16) * 32 + g4 * 8]);
#pragma unroll
    for (int ni = 0; ni < 4; ni++)
      bfr[ni] = *reinterpret_cast<const bf16x8*>(
          &ldsB[cur][(wc * 64 + ni * 16 + r16) * 32 + g4 * 8]);
    __builtin_amdgcn_s_setprio(1);
#pragma unroll
    for (int mi = 0; mi < 4; mi++)
#pragma unroll
      for (int ni = 0; ni < 4; ni++)
        acc[mi][ni] = __builtin_amdgcn_mfma_f32_16x16x32_bf16(
            af[mi], bfr[ni], acc[mi][ni], 0, 0, 0);
    __builtin_amdgcn_s_setprio(0);
    barrier_raw();  // (B) all waves done reading cur -> next iter may overwrite
    cur ^= 1;
  }

  // ---- epilogue via per-wave-private LDS transpose buffer (4KB each).
  // All DMA drained (last iter waited vmcnt(0)), all reads done (barrier B).
  float* shf = reinterpret_cast<float*>(&ldsA[0][0]) + w * 1024;  // 16x64 f32
  const int bq = m0 >> 11;                 // batch index
  const int rloc = (m0 & 2047) + wr * 64;  // local kv base for V^T
#pragma unroll
  for (int mi = 0; mi < 4; mi++) {
#pragma unroll
    for (int ni = 0; ni < 4; ni++)
#pragma unroll
      for (int i = 0; i < 4; i++) {
        const int rl = g4 * 4 + i;             // C/D row (m89-verified)
        const int cl = ni * 16 + r16;          // C/D col
        shf[rl * 64 + ((cl + 4 * rl) & 63)] = acc[mi][ni][i];  // rot-swizzle
      }
    wait_lds();
    if (z == 2) {
      // transposed read -> Vt[(bq*1024 + n0 + wc*64 + cl)][kv]
#pragma unroll
      for (int cc = 0; cc < 4; cc++) {
        const int cl = (lane >> 2) + cc * 16;
        const int rl0 = (lane & 3) * 4;
        float v0 = shf[(rl0 + 0) * 64 + ((cl + 4 * (rl0 + 0)) & 63)];
        float v1 = shf[(rl0 + 1) * 64 + ((cl + 4 * (rl0 + 1)) & 63)];
        float v2 = shf[(rl0 + 2) * 64 + ((cl + 4 * (rl0 + 2)) & 63)];
        float v3 = shf[(rl0 + 3) * 64 + ((cl + 4 * (rl0 + 3)) & 63)];
        bf16x4 o;
        o[0] = (bf16)v0; o[1] = (bf16)v1; o[2] = (bf16)v2; o[3] = (bf16)v3;
        *reinterpret_cast<bf16x4*>(
            Y + (size_t)(bq * 1024 + n0 + wc * 64 + cl) * 2048 +
            rloc + mi * 16 + rl0) = o;
      }
    } else {
#pragma unroll
      for (int cc = 0; cc < 4; cc++) {
        const int row = g4 + cc * 4;
        const int c0 = r16 * 4;
        const f32x4 vv = *reinterpret_cast<const f32x4*>(
            &shf[row * 64 + ((c0 + 4 * row) & 63)]);
        bf16x4 o;
        o[0] = (bf16)vv[0]; o[1] = (bf16)vv[1]; o[2] = (bf16)vv[2]; o[3] = (bf16)vv[3];
        *reinterpret_cast<bf16x4*>(
            Y + (size_t)(m0 + wr * 64 + mi * 16 + row) * DMODEL + n0 + wc * 64 + c0) = o;
      }
    }
    wait_lds();
  }
}

// ---------------------------------------------------------------- attention
// 32x32 MFMA flash attn. K and V^T tiles staged into LDS via coalesced
// global_load_lds DMA (pre-swizzled sources, G21); 2-barrier counted-vmcnt
// pipeline so the prefetch DMA is never drained inside the loop (T4).
// Fixed-shift exp2 softmax (exact by shift invariance); P in registers via
// cvt_pk+permlane32_swap; row-sum via ones-MFMA; shuffle-free epilogue.
__global__ __launch_bounds__(256, 4) void attn_kernel(const bf16* __restrict__ Qp,
                                                      const bf16* __restrict__ Kp,
                                                      const bf16* __restrict__ Vtp,
                                                      float* __restrict__ Out) {
  // ldsK slot [kv][c'] holds K[kv][c' ^ 8*(kv&7)]   (c' = head-dim col)
  // ldsV slot [d][c']  holds Vt[d][kv0 + (c' ^ 8*(d&7))]  (c' = kv col)
  __shared__ bf16 ldsK[2][64 * 64];
  __shared__ bf16 ldsV[2][64 * 64];

  const int tid = threadIdx.x;
  const int lane = tid & 63;
  const int w = tid >> 6;
  const int l31 = lane & 31, hi = lane >> 5;
  const int bh = blockIdx.x;  // b*NH + h
  const int b = bh >> 4;
  const int h = bh & 15;
  const int q0 = blockIdx.y * 128 + w * 32;

  const bf16* __restrict__ Qb = Qp + (size_t)(b * S_LEN) * DMODEL + h * 64;
  const bf16* __restrict__ Kb = Kp + (size_t)(b * S_LEN) * DMODEL + h * 64;
  const bf16* __restrict__ Vtb = Vtp + (size_t)bh * 64 * S_LEN;  // [64][2048]

  // Q fragments (B-operand, 32x32x16): lane holds Q[q0+l31][s*16+hi*8+j]
  bf16x8 qf[4];
#pragma unroll
  for (int s = 0; s < 4; s++)
    qf[s] = *reinterpret_cast<const bf16x8*>(
        &Qb[(size_t)(q0 + l31) * DMODEL + s * 16 + hi * 8]);

  f32x16 oacc[2], lacc;
  oacc[0] = (f32x16)0.f;
  oacc[1] = (f32x16)0.f;
  lacc = (f32x16)0.f;

  bf16x8 ones;
#pragma unroll
  for (int j = 0; j < 8; j++) ones[j] = (bf16)1.0f;

  const float C2 = 0.04508422002778011f;  // log2(e)/32
  const float M2 = 1.0f;                  // fixed shift (exp2 domain)

  const int srow = tid >> 3;           // 0..31
  const int scol = (tid & 7) * 8;      // 0..56
  const int swz = (srow & 7) * 8;      // source pre-swizzle (G21); (srow+32)&7==srow&7

  auto stageK = [&](int buf, int kv0) {
    gload_lds16(&Kb[(size_t)(kv0 + srow) * DMODEL + (scol ^ swz)],
                &ldsK[buf][tid * 8]);
    gload_lds16(&Kb[(size_t)(kv0 + 32 + srow) * DMODEL + (scol ^ swz)],
                &ldsK[buf][2048 + tid * 8]);
  };
  auto stageV = [&](int buf, int kv0) {
    gload_lds16(&Vtb[(size_t)srow * S_LEN + kv0 + (scol ^ swz)],
                &ldsV[buf][tid * 8]);
    gload_lds16(&Vtb[(size_t)(32 + srow) * S_LEN + kv0 + (scol ^ swz)],
                &ldsV[buf][2048 + tid * 8]);
  };

  stageK(0, 0);
  stageV(0, 0);
  wait_vm0();
  barrier_raw();
  int cur = 0;

  union U { u32x4 u; bf16x8 v; };

  constexpr int NT = S_LEN / 64;
  for (int it = 0; it < NT; it++) {
    const bool pf = (it + 1 < NT);
    if (pf) {
      stageK(cur ^ 1, (it + 1) * 64);  // 4 DMA issued; fly across this tile
      stageV(cur ^ 1, (it + 1) * 64);
      wait_vm4();                      // cur's 4 (issued last iter) complete
    } else {
      wait_vm0();
    }
    barrier_raw();  // (A) cur staged for all waves

    // --- QK^T per kv-half, immediate exp+pack (live sacc = 16 regs)
    U pa[2][2];  // pa[kvh][sh]: A[q=l31][kv = kvh*32 + sh*16 + hi*8 + j]
#pragma unroll
    for (int kvh = 0; kvh < 2; kvh++) {
      f32x16 sacc = (f32x16)0.f;
      const int kv = kvh * 32 + l31;
      __builtin_amdgcn_s_setprio(1);
#pragma unroll
      for (int s = 0; s < 4; s++) {
        const bf16x8 kf = *reinterpret_cast<const bf16x8*>(
            &ldsK[cur][kv * 64 + ((s * 16 + hi * 8) ^ ((l31 & 7) * 8))]);
        sacc = __builtin_amdgcn_mfma_f32_32x32x16_bf16(kf, qf[s], sacc, 0, 0, 0);
      }
      __builtin_amdgcn_s_setprio(0);

      // p = 2^(s*C2 - M2); element-independent, no reductions
#pragma unroll
      for (int r = 0; r < 16; r++) sacc[r] = exp2f(fmaf(sacc[r], C2, -M2));

      uint32_t a0 = cvtpk(sacc[0], sacc[1]);
      uint32_t b0 = cvtpk(sacc[4], sacc[5]);
      pl32swap(a0, b0);
      uint32_t a1 = cvtpk(sacc[2], sacc[3]);
      uint32_t b1 = cvtpk(sacc[6], sacc[7]);
      pl32swap(a1, b1);
      pa[kvh][0].u = (u32x4){a0, a1, b0, b1};
      uint32_t a2 = cvtpk(sacc[8], sacc[9]);
      uint32_t b2 = cvtpk(sacc[12], sacc[13]);
      pl32swap(a2, b2);
      uint32_t a3 = cvtpk(sacc[10], sacc[11]);
      uint32_t b3 = cvtpk(sacc[14], sacc[15]);
      pl32swap(a3, b3);
      pa[kvh][1].u = (u32x4){a2, a3, b2, b3};
    }

    // --- PV + row-sum: oacc[db] += P*V ; lacc += P*ones
    __builtin_amdgcn_s_setprio(1);
#pragma unroll
    for (int kvh = 0; kvh < 2; kvh++)
#pragma unroll
      for (int sh = 0; sh < 2; sh++) {
        const int kvb = kvh * 32 + sh * 16 + hi * 8;
        lacc = __builtin_amdgcn_mfma_f32_32x32x16_bf16(pa[kvh][sh].v, ones,
                                                       lacc, 0, 0, 0);
#pragma unroll
        for (int db = 0; db < 2; db++) {
          const int d = db * 32 + l31;
          const bf16x8 vf = *reinterpret_cast<const bf16x8*>(
              &ldsV[cur][d * 64 + (kvb ^ ((d & 7) * 8))]);
          oacc[db] = __builtin_amdgcn_mfma_f32_32x32x16_bf16(pa[kvh][sh].v, vf,
                                                             oacc[db], 0, 0, 0);
        }
      }
    __builtin_amdgcn_s_setprio(0);

    barrier_raw();  // (B) all waves done reading cur
    cur ^= 1;
  }

  // --- epilogue: Out[b][q0+qrow][h*64 + db*32 + l31] = oacc/lacc
#pragma unroll
  for (int r = 0; r < 16; r++) {
    const int qrow = (r & 3) + 8 * (r >> 2) + 4 * hi;
    const float inv_l = 1.0f / lacc[r];
    float* op = Out + (size_t)(b * S_LEN + q0 + qrow) * DMODEL + h * 64 + l31;
    op[0] = oacc[0][r] * inv_l;
    op[32] = oacc[1][r] * inv_l;
  }
}

// ---------------------------------------------------------------- launch
extern "C" void kernel_launch(void* const* d_in, const int* in_sizes, int n_in,
                              void* d_out, int out_size, void* d_ws, size_t ws_size,
                              hipStream_t stream) {
  const float* q = (const float*)d_in[0];
  const float* k = (const float*)d_in[1];
  const float* v = (const float*)d_in[2];
  const float* wq = (const float*)d_in[3];
  const float* wk = (const float*)d_in[4];
  const float* wv = (const float*)d_in[5];
  bf16* ws = (bf16*)d_ws;
  bf16* Xc = ws;
  bf16* Wc = ws + WC_OFF;
  bf16* Pp = ws + PP_OFF;
  float* out = (float*)d_out;

  CvtArgs ca;
  ca.s[0] = q;  ca.s[1] = k;  ca.s[2] = v;
  ca.s[3] = wq; ca.s[4] = wk; ca.s[5] = wv;
  ca.d[0] = Xc;          ca.d[1] = Xc + NX;     ca.d[2] = Xc + 2 * NX;
  ca.d[3] = Wc;          ca.d[4] = Wc + NW;     ca.d[5] = Wc + 2 * NW;
  ca.n[0] = ca.n[1] = ca.n[2] = (int)NX;
  ca.n[3] = ca.n[4] = ca.n[5] = (int)NW;
  cvt_f32_bf16<<<dim3(4096, 6, 1), dim3(256), 0, stream>>>(ca);

  proj_gemm<<<dim3(64, 8, 3), dim3(256), 0, stream>>>(Xc, Wc, Pp);

  // grid: x = b*NH+h (64), y = q-tile (16)
  attn_kernel<<<dim3(BATCH * NH, S_LEN / 128, 1), dim3(256), 0, stream>>>(
      Pp, Pp + NX, Pp + 2 * NX, out);
}